// Round 5
// baseline (507.657 us; speedup 1.0000x reference)
//
#include <hip/hip_runtime.h>
#include <cstdint>
#include <cstddef>

// TSPEdgeEmbedding on MI355X — R5: two-phase (selection / expansion).
//
// Outputs (flat float32 in d_out, in reference return order):
//   [0, 2048000)              x = init_embeddings passthrough [B*n, D]
//   [2048000, 2848000)        edge_index row 0 (src), as float
//   [2848000, 3648000)        edge_index row 1 (dst), as float
//   [3648000, 106048000)      edge_emb [B*n*k, D] = dist*W + b
//
// R4 post-mortem: fused per-round edge_emb stores made the device-wide
// write stream ~16000 interleaved 512 B streams -> effective HBM write
// BW ~2.5-3 TB/s (vs 6.3 for the dense fill), a ~130-150 us memory term
// that dominated. R5 splits:
//   Phase 1 (selection): one wave per node, DPP/SALU wave-min extraction
//     (R4 machinery, zero DS ops per round). Rank lane keeps (dist, j);
//     ends with coalesced writes of dist -> d_ws scratch (3.2 MB), dst,
//     src, and the x passthrough. ~18 MB of writes total: compute-bound.
//   Phase 2 (expansion): fill-shaped streaming kernel over the 409.6 MB
//     edge_emb region: dense sequential float4 stores, fixed per-thread
//     column => W/b in registers, dist via L2-hit scalar load.
// Fallback: if ws_size < 3.2 MB, launch the R4 fused kernel instead.

namespace {

constexpr int kB  = 16;
constexpr int kN  = 1000;
constexpr int kD  = 128;
constexpr int kK  = 50;
constexpr int kCPL = 16;                               // candidates per lane (64*16 = 1024 >= 1000)
constexpr int kNodesPerBlock = 4;                      // 4 waves / 256-thread block
constexpr int kBlocksPerBatch = kN / kNodesPerBlock;   // 250 (exact)

constexpr size_t X_SZ    = (size_t)kB * kN * kD;   // 2,048,000
constexpr size_t E_SZ    = (size_t)kB * kN * kK;   // 800,000
constexpr size_t SRC_OFF = X_SZ;
constexpr size_t DST_OFF = X_SZ + E_SZ;
constexpr size_t EMB_OFF = X_SZ + 2 * E_SZ;
constexpr size_t EMB_F4  = (E_SZ * kD) / 4;        // 25,600,000 float4s

__device__ __forceinline__ double pack_key(float dd, int j) {
  const unsigned long long u =
      ((unsigned long long)__float_as_uint(dd) << 32) | (unsigned)j;
  return __longlong_as_double((long long)u);
}

// min over self and DPP-permuted self (stays on the VALU pipe)
template<int CTRL>
__device__ __forceinline__ unsigned dpp_min_u32(unsigned x) {
  const unsigned y = (unsigned)__builtin_amdgcn_update_dpp(
      0, (int)x, CTRL, 0xF, 0xF, true);
  return x < y ? x : y;
}

// ---------------------------------------------------------------------------
// Phase 1: selection. One wave per node. Writes x, src, dst, and dist->dbuf.
// ---------------------------------------------------------------------------
__global__ __launch_bounds__(256)
void tsp_select_kernel(const float* __restrict__ locs,
                       const float* __restrict__ init_emb,
                       float* __restrict__ out,
                       float* __restrict__ dbuf)
{
#pragma clang fp contract(off)   // match numpy/XLA: separate mul/add rounding, no FMA
  const int tid  = threadIdx.x;
  const int wave = tid >> 6;
  const int lane = tid & 63;
  const int blk  = blockIdx.x;
  const int b    = blk / kBlocksPerBatch;
  const int node_in_b = (blk % kBlocksPerBatch) * kNodesPerBlock + wave;
  const int node = b * kN + node_in_b;    // global node id (= src index)

  // ---- independent outputs first: overlap their traffic with selection ----
  {
    const float2* srcp = reinterpret_cast<const float2*>(init_emb + (size_t)node * kD);
    float2* dstp = reinterpret_cast<float2*>(out + (size_t)node * kD);
    dstp[lane] = srcp[lane];
  }
  if (lane < kK) {
    out[SRC_OFF + (size_t)node * kK + lane] = (float)node;
  }

  // ---- stage this batch's locs into LDS (shared by the 4 waves) ----
  __shared__ __align__(16) float2 sloc[kN];
  {
    const float4* gl4 = reinterpret_cast<const float4*>(locs + (size_t)b * kN * 2);
    float4* sl4 = reinterpret_cast<float4*>(sloc);
    for (int t = tid; t < kN / 2; t += 256) sl4[t] = gl4[t];
  }
  __syncthreads();

  const float2 my = sloc[node_in_b];

  // ---- per-lane candidate keys (registers), strided ownership ----
  double key[kCPL];
#pragma unroll
  for (int s = 0; s < kCPL; ++s) {
    const int j = lane + (s << 6);
    const bool valid = (j < kN) && (j != node_in_b);
    const float2 pj = sloc[(j < kN) ? j : 0];     // conflict-free: lanes consecutive
    const float dx = my.x - pj.x;
    const float dy = my.y - pj.y;
    const float d2 = dx * dx + dy * dy;           // contract(off): matches np bitwise
    float dd = sqrtf(d2 + 1e-12f);
    if (!valid) dd = INFINITY;                    // hi = 0x7F800000, still a finite double key
    key[s] = pack_key(dd, j);
  }

  // ---- one-time per-lane bitonic sort (ascending), 80 CE, all in VGPRs ----
#pragma unroll
  for (int kk = 2; kk <= kCPL; kk <<= 1) {
#pragma unroll
    for (int jj = kk >> 1; jj > 0; jj >>= 1) {
#pragma unroll
      for (int i = 0; i < kCPL; ++i) {
        const int l2 = i ^ jj;
        if (l2 > i) {
          const double a  = key[i];
          const double c  = key[l2];
          const double lo = fmin(a, c);
          const double hi = fmax(a, c);
          if ((i & kk) == 0) { key[i] = lo; key[l2] = hi; }
          else               { key[i] = hi; key[l2] = lo; }
        }
      }
    }
  }

  float res_d = 0.0f;                    // lane r (< kK) ends holding rank-r dist
  int   res_j = 0;                       // ... and rank-r neighbor index
  const double INFK = __builtin_inf();   // > every key; never equals one

  // ---- 50 extraction rounds, zero DS ops per round ----
#pragma unroll 1
  for (int r = 0; r < kK; ++r) {
    const unsigned long long u0 = (unsigned long long)__double_as_longlong(key[0]);
    const unsigned head_d = (unsigned)(u0 >> 32);   // f32 dist bits (>= 0)
    const unsigned head_j = (unsigned)u0;

    // wave-min of head_d: 4 DPP steps (VALU) -> per-16-row min in all lanes
    unsigned v = head_d;
    v = dpp_min_u32<0xB1>(v);    // quad_perm [1,0,3,2]  (xor 1)
    v = dpp_min_u32<0x4E>(v);    // quad_perm [2,3,0,1]  (xor 2)
    v = dpp_min_u32<0x141>(v);   // row_half_mirror      (xor 4 at group level)
    v = dpp_min_u32<0x140>(v);   // row_mirror           (xor 8 at group level)
    // rows -> wave via readlane + scalar min (u32 order == f32 order, d >= 0)
    const unsigned q0 = (unsigned)__builtin_amdgcn_readlane((int)v, 0);
    const unsigned q1 = (unsigned)__builtin_amdgcn_readlane((int)v, 16);
    const unsigned q2 = (unsigned)__builtin_amdgcn_readlane((int)v, 32);
    const unsigned q3 = (unsigned)__builtin_amdgcn_readlane((int)v, 48);
    const unsigned qa = q0 < q1 ? q0 : q1;
    const unsigned qb = q2 < q3 ? q2 : q3;
    const unsigned mu = qa < qb ? qa : qb;          // wave-uniform (SGPR)

    // winner index: lowest matching lane; exact dist-tie -> min j (rare)
    const unsigned long long msk = __ballot(head_d == mu);
    unsigned jwin = (unsigned)__builtin_amdgcn_readlane(
        (int)head_j, __ffsll((long long)msk) - 1);
    if (__popcll(msk) > 1) {
      unsigned long long mm = msk;
      jwin = 0xFFFFFFFFu;
      while (mm) {
        const int l = __ffsll((long long)mm) - 1;
        const unsigned jj = (unsigned)__builtin_amdgcn_readlane((int)head_j, l);
        jwin = jj < jwin ? jj : jwin;
        mm &= mm - 1;
      }
    }

    if (lane == r) { res_j = (int)jwin; res_d = __uint_as_float(mu); }

    // pop: exactly one lane's head equals (mu, jwin) -- shift its list
    const unsigned long long wk = ((unsigned long long)mu << 32) | jwin;
    const bool pop = (u0 == wk);
#pragma unroll
    for (int s = 0; s < kCPL - 1; ++s) key[s] = pop ? key[s + 1] : key[s];
    key[kCPL - 1] = pop ? INFK : key[kCPL - 1];
  }

  // ---- coalesced rank outputs: dist scratch + edge_index dst ----
  if (lane < kK) {
    dbuf[(size_t)node * kK + lane] = res_d;
    out[DST_OFF + (size_t)node * kK + lane] = (float)(b * kN + res_j);
  }
}

// ---------------------------------------------------------------------------
// Phase 2: expansion. Dense sequential float4 stores over edge_emb.
// Grid-stride = 2048*256 threads; stride in float4 units is a multiple of 32
// => each thread's column (i & 31) is FIXED => W/b float4 loaded once.
// ---------------------------------------------------------------------------
__global__ __launch_bounds__(256)
void tsp_expand_kernel(const float* __restrict__ dbuf,
                       const float* __restrict__ W,
                       const float* __restrict__ bias,
                       float* __restrict__ out)
{
#pragma clang fp contract(off)
  const size_t g      = (size_t)blockIdx.x * blockDim.x + threadIdx.x;
  const size_t stride = (size_t)gridDim.x * blockDim.x;   // multiple of 32

  const int c4 = (int)(g & 31);                 // fixed float4-column per thread
  const float4 w4 = reinterpret_cast<const float4*>(W)[c4];
  const float4 b4 = reinterpret_cast<const float4*>(bias)[c4];
  float4* eout = reinterpret_cast<float4*>(out + EMB_OFF);

  for (size_t i = g; i < EMB_F4; i += stride) {
    const float dist = dbuf[i >> 5];            // row = i/32 (128 floats/row)
    float4 v;
    v.x = dist * w4.x + b4.x;                   // contract(off): mul+add, bit-exact
    v.y = dist * w4.y + b4.y;
    v.z = dist * w4.z + b4.z;
    v.w = dist * w4.w + b4.w;
    eout[i] = v;
  }
}

// ---------------------------------------------------------------------------
// Fallback: R4 fused kernel (used only if ws_size is too small for dbuf).
// ---------------------------------------------------------------------------
__global__ __launch_bounds__(256)
void tsp_edge_fused(const float* __restrict__ locs,
                    const float* __restrict__ init_emb,
                    const float* __restrict__ W,
                    const float* __restrict__ bias,
                    float* __restrict__ out)
{
#pragma clang fp contract(off)
  const int tid  = threadIdx.x;
  const int wave = tid >> 6;
  const int lane = tid & 63;
  const int blk  = blockIdx.x;
  const int b    = blk / kBlocksPerBatch;
  const int node_in_b = (blk % kBlocksPerBatch) * kNodesPerBlock + wave;
  const int node = b * kN + node_in_b;

  {
    const float2* srcp = reinterpret_cast<const float2*>(init_emb + (size_t)node * kD);
    float2* dstp = reinterpret_cast<float2*>(out + (size_t)node * kD);
    dstp[lane] = srcp[lane];
  }
  if (lane < kK) {
    out[SRC_OFF + (size_t)node * kK + lane] = (float)node;
  }

  __shared__ __align__(16) float2 sloc[kN];
  {
    const float4* gl4 = reinterpret_cast<const float4*>(locs + (size_t)b * kN * 2);
    float4* sl4 = reinterpret_cast<float4*>(sloc);
    for (int t = tid; t < kN / 2; t += 256) sl4[t] = gl4[t];
  }
  __syncthreads();

  const float2 my = sloc[node_in_b];

  double key[kCPL];
#pragma unroll
  for (int s = 0; s < kCPL; ++s) {
    const int j = lane + (s << 6);
    const bool valid = (j < kN) && (j != node_in_b);
    const float2 pj = sloc[(j < kN) ? j : 0];
    const float dx = my.x - pj.x;
    const float dy = my.y - pj.y;
    const float d2 = dx * dx + dy * dy;
    float dd = sqrtf(d2 + 1e-12f);
    if (!valid) dd = INFINITY;
    key[s] = pack_key(dd, j);
  }

#pragma unroll
  for (int kk = 2; kk <= kCPL; kk <<= 1) {
#pragma unroll
    for (int jj = kk >> 1; jj > 0; jj >>= 1) {
#pragma unroll
      for (int i = 0; i < kCPL; ++i) {
        const int l2 = i ^ jj;
        if (l2 > i) {
          const double a  = key[i];
          const double c  = key[l2];
          const double lo = fmin(a, c);
          const double hi = fmax(a, c);
          if ((i & kk) == 0) { key[i] = lo; key[l2] = hi; }
          else               { key[i] = hi; key[l2] = lo; }
        }
      }
    }
  }

  const float2 wv = reinterpret_cast<const float2*>(W)[lane];
  const float2 bv = reinterpret_cast<const float2*>(bias)[lane];
  float* erow = out + EMB_OFF + (size_t)node * (kK * kD) + lane * 2;

  int res_j = 0;
  const double INFK = __builtin_inf();

#pragma unroll 1
  for (int r = 0; r < kK; ++r) {
    const unsigned long long u0 = (unsigned long long)__double_as_longlong(key[0]);
    const unsigned head_d = (unsigned)(u0 >> 32);
    const unsigned head_j = (unsigned)u0;

    unsigned v = head_d;
    v = dpp_min_u32<0xB1>(v);
    v = dpp_min_u32<0x4E>(v);
    v = dpp_min_u32<0x141>(v);
    v = dpp_min_u32<0x140>(v);
    const unsigned q0 = (unsigned)__builtin_amdgcn_readlane((int)v, 0);
    const unsigned q1 = (unsigned)__builtin_amdgcn_readlane((int)v, 16);
    const unsigned q2 = (unsigned)__builtin_amdgcn_readlane((int)v, 32);
    const unsigned q3 = (unsigned)__builtin_amdgcn_readlane((int)v, 48);
    const unsigned qa = q0 < q1 ? q0 : q1;
    const unsigned qb = q2 < q3 ? q2 : q3;
    const unsigned mu = qa < qb ? qa : qb;

    const unsigned long long msk = __ballot(head_d == mu);
    unsigned jwin = (unsigned)__builtin_amdgcn_readlane(
        (int)head_j, __ffsll((long long)msk) - 1);
    if (__popcll(msk) > 1) {
      unsigned long long mm = msk;
      jwin = 0xFFFFFFFFu;
      while (mm) {
        const int l = __ffsll((long long)mm) - 1;
        const unsigned jj = (unsigned)__builtin_amdgcn_readlane((int)head_j, l);
        jwin = jj < jwin ? jj : jwin;
        mm &= mm - 1;
      }
    }

    if (lane == r) res_j = (int)jwin;

    const float dist = __uint_as_float(mu);
    float2 vv;
    vv.x = dist * wv.x + bv.x;
    vv.y = dist * wv.y + bv.y;
    *reinterpret_cast<float2*>(erow) = vv;
    erow += kD;

    const unsigned long long wk = ((unsigned long long)mu << 32) | jwin;
    const bool pop = (u0 == wk);
#pragma unroll
    for (int s = 0; s < kCPL - 1; ++s) key[s] = pop ? key[s + 1] : key[s];
    key[kCPL - 1] = pop ? INFK : key[kCPL - 1];
  }

  if (lane < kK) {
    out[DST_OFF + (size_t)node * kK + lane] = (float)(b * kN + res_j);
  }
}

} // namespace

extern "C" void kernel_launch(void* const* d_in, const int* in_sizes, int n_in,
                              void* d_out, int out_size, void* d_ws, size_t ws_size,
                              hipStream_t stream) {
  const float* locs = (const float*)d_in[0];   // [16,1000,2]
  const float* emb  = (const float*)d_in[1];   // [16,1000,128]
  const float* W    = (const float*)d_in[2];   // [1,128]
  const float* bias = (const float*)d_in[3];   // [128]
  float* out = (float*)d_out;

  const size_t need = (size_t)kB * kN * kK * sizeof(float);   // 3.2 MB dist scratch

  if (d_ws != nullptr && ws_size >= need) {
    float* dbuf = (float*)d_ws;
    dim3 grid1(kB * kBlocksPerBatch);   // 4000 blocks = 16000 waves = 1 per node
    dim3 block(256);
    hipLaunchKernelGGL(tsp_select_kernel, grid1, block, 0, stream,
                       locs, emb, out, dbuf);
    dim3 grid2(2048);                   // fill-shaped streaming expansion
    hipLaunchKernelGGL(tsp_expand_kernel, grid2, block, 0, stream,
                       dbuf, W, bias, out);
  } else {
    dim3 grid(kB * kBlocksPerBatch);
    dim3 block(256);
    hipLaunchKernelGGL(tsp_edge_fused, grid, block, 0, stream,
                       locs, emb, W, bias, out);
  }
}